// Round 1
// 1377.378 us; speedup vs baseline: 1.0078x; 1.0078x over previous
//
#include <hip/hip_runtime.h>
#include <math.h>

#define DEV __device__ __forceinline__

typedef __attribute__((ext_vector_type(8))) short short8;   // 8 bf16 = 4 VGPRs (MFMA frag)
typedef __attribute__((ext_vector_type(4))) float f32x4;    // MFMA 16x16 accum

DEV unsigned short f2bf(float f) {
  union { float f; unsigned int i; } v; v.f = f;
  unsigned int r = v.i + 0x7fffu + ((v.i >> 16) & 1u);
  return (unsigned short)(r >> 16);
}

DEV void lds16(const void* g, void* l) {
  __builtin_amdgcn_global_load_lds((__attribute__((address_space(1))) void*)(g),
                                   (__attribute__((address_space(3))) void*)(l), 16, 0, 0);
}

// ---------------- weight prep ----------------

__global__ void transpose_g(const float* __restrict__ src, unsigned short* __restrict__ dst,
                            int Ksz, int Nsz) {
  __shared__ float tile[32][33];
  const int tx = threadIdx.x, ty = threadIdx.y;
  const int n0 = blockIdx.x * 32, k0 = blockIdx.y * 32;
  const size_t base = (size_t)blockIdx.z * Ksz * Nsz;
#pragma unroll
  for (int i = 0; i < 4; ++i)
    tile[ty + i * 8][tx] = src[base + (size_t)(k0 + ty + i * 8) * Nsz + n0 + tx];
  __syncthreads();
#pragma unroll
  for (int i = 0; i < 4; ++i)
    dst[base + (size_t)(n0 + ty + i * 8) * Ksz + k0 + tx] = f2bf(tile[tx][ty + i * 8]);
}

// Wq/Wk/Wv (L,H,512,64) -> wqkvT [L][1536][512], col order n = mat*512 + h*64 + dk
__global__ void pack_qkvT(const float* __restrict__ Wq, const float* __restrict__ Wk,
                          const float* __restrict__ Wv, unsigned short* __restrict__ dst) {
  __shared__ float tile[32][33];
  const int tx = threadIdx.x, ty = threadIdx.y;
  const int n0 = blockIdx.x * 32, k0 = blockIdx.y * 32, l = blockIdx.z;
  const int mat = n0 >> 9, hh = (n0 >> 6) & 7, dk0 = n0 & 63;
  const float* W = (mat == 0) ? Wq : (mat == 1) ? Wk : Wv;
  const float* Wl = W + ((size_t)l * 8 + hh) * 512 * 64;
#pragma unroll
  for (int i = 0; i < 4; ++i)
    tile[ty + i * 8][tx] = Wl[(size_t)(k0 + ty + i * 8) * 64 + dk0 + tx];
  __syncthreads();
#pragma unroll
  for (int i = 0; i < 4; ++i)
    dst[(size_t)l * 1536 * 512 + (size_t)(n0 + ty + i * 8) * 512 + k0 + tx] =
        f2bf(tile[tx][ty + i * 8]);
}

__global__ void pack_bias(const float* __restrict__ bq, const float* __restrict__ bk,
                          const float* __restrict__ bv, float* __restrict__ dst) {
  int i = blockIdx.x * 256 + threadIdx.x;
  if (i >= 6 * 1536) return;
  int l = i / 1536, c = i % 1536;
  float v = (c < 512) ? bq[l * 512 + c] : (c < 1024) ? bk[l * 512 + (c - 512)]
                                                     : bv[l * 512 + (c - 1024)];
  dst[i] = v;
}

// ---------------- embed + positional encoding ----------------
__global__ void embed_kernel(const int* __restrict__ ids, const float* __restrict__ emb,
                             const float* __restrict__ cls, float* __restrict__ x) {
  int idx = blockIdx.x * 256 + threadIdx.x;   // over 8208*512
  int m = idx >> 9, d = idx & 511;
  int b = m / 513, t = m % 513;
  float v = (t == 0) ? cls[d] : emb[(size_t)ids[b * 512 + (t - 1)] * 512 + d];
  float fr = -(float)(d & ~1) * (9.2103403719761836f / 512.0f);
  float ang = (float)t * expf(fr);
  float pe = (d & 1) ? cosf(ang) : sinf(ang);
  x[idx] = v + pe;
}

// ---------------- layernorm: x(f32)[8208][512] -> h(bf16), one wave per row ----------------
__global__ __launch_bounds__(256) void ln_kernel(const float* __restrict__ x,
                                                 const float* __restrict__ g,
                                                 const float* __restrict__ bb,
                                                 unsigned short* __restrict__ h) {
  int wid = threadIdx.x >> 6, lane = threadIdx.x & 63;
  int m = blockIdx.x * 4 + wid;
  const float* xr = x + (size_t)m * 512;
  float4 a = *(const float4*)(xr + lane * 8);
  float4 c = *(const float4*)(xr + lane * 8 + 4);
  float s = a.x + a.y + a.z + a.w + c.x + c.y + c.z + c.w;
  float q = a.x * a.x + a.y * a.y + a.z * a.z + a.w * a.w +
            c.x * c.x + c.y * c.y + c.z * c.z + c.w * c.w;
#pragma unroll
  for (int d = 1; d < 64; d <<= 1) { s += __shfl_xor(s, d); q += __shfl_xor(q, d); }
  float mu = s * (1.f / 512.f);
  float var = q * (1.f / 512.f) - mu * mu;
  float rs = 1.f / sqrtf(var + 1e-5f);
  float4 g0 = *(const float4*)(g + lane * 8), g1 = *(const float4*)(g + lane * 8 + 4);
  float4 b0 = *(const float4*)(bb + lane * 8), b1 = *(const float4*)(bb + lane * 8 + 4);
  short8 ov;
  ov[0] = (short)f2bf((a.x - mu) * rs * g0.x + b0.x);
  ov[1] = (short)f2bf((a.y - mu) * rs * g0.y + b0.y);
  ov[2] = (short)f2bf((a.z - mu) * rs * g0.z + b0.z);
  ov[3] = (short)f2bf((a.w - mu) * rs * g0.w + b0.w);
  ov[4] = (short)f2bf((c.x - mu) * rs * g1.x + b1.x);
  ov[5] = (short)f2bf((c.y - mu) * rs * g1.y + b1.y);
  ov[6] = (short)f2bf((c.z - mu) * rs * g1.z + b1.z);
  ov[7] = (short)f2bf((c.w - mu) * rs * g1.w + b1.w);
  *(short8*)(h + (size_t)m * 512 + lane * 8) = ov;
}

// ---------------- GEMM: C[M][N] = A[Mpad][lda](bf16) * Bt[N][lda]^T (bf16) + bias ---------
// 128x128 tile, BK=64, 4 waves (2x2), 16x16x32 MFMA, global_load_lds w/ XOR-swizzled source.
// XCD-aware bijective block swizzle (m204).
// Split-K support: blockIdx.z selects K-chunk of length K (elements) at column z*K of lda-wide
// rows. Chunk 0 of EPI==2 does the residual += (sole writer of Cres); chunks >0 store f32
// partials to part[(z-1)*M*N + ...], combined later by reduce3 (no atomics -> deterministic).
// EPI: 0 = bf16 out, 1 = bf16 relu out, 2 = f32 residual add (+split-K), 3 = qkv (q,k->big; v->vT)
template <int EPI>
__global__ __launch_bounds__(256) void gemm_bt(const unsigned short* __restrict__ A,
                                               const unsigned short* __restrict__ Bt,
                                               const float* __restrict__ bias,
                                               unsigned short* __restrict__ Cbf,
                                               float* __restrict__ Cres,
                                               unsigned short* __restrict__ vT,
                                               float* __restrict__ part,
                                               int M, int N, int K, int lda) {
  __shared__ __align__(16) unsigned short As[128 * 64];
  __shared__ __align__(16) unsigned short Bs[128 * 64];
  const int tid = threadIdx.x, w = tid >> 6, lane = tid & 63;
  const int l15 = lane & 15, l4 = lane >> 4;
  // XCD-aware bijective swizzle over linear block id (within each z-slice)
  const int gx = gridDim.x;
  const int nwg = gx * gridDim.y;
  const int id = blockIdx.y * gx + blockIdx.x;
  const int xcd = id & 7, orig = id >> 3;
  const int qq = nwg >> 3, rr = nwg & 7;
  const int newid = (xcd < rr ? xcd * (qq + 1) : rr * (qq + 1) + (xcd - rr) * qq) + orig;
  const int m0 = (newid % gx) * 128, n0 = (newid / gx) * 128;
  const int wm = (w >> 1) * 64, wn = (w & 1) * 64;
  const int kbase = blockIdx.z * K;      // split-K column offset
  f32x4 acc[4][4] = {};
  const int nk = K >> 6;
  for (int kt = 0; kt < nk; ++kt) {
#pragma unroll
    for (int r = 0; r < 4; ++r) {
      int ol = (r * 4 + w) * 1024 + lane * 16;      // byte offset in 16KB tile
      int ra = ol >> 7, cp = (ol >> 4) & 7;
      int co = ((cp ^ (ra & 7)) * 8) + kt * 64;     // swizzled source chunk (ushort units)
      lds16(A + (size_t)(m0 + ra) * lda + kbase + co, (char*)As + (r * 4 + w) * 1024);
      lds16(Bt + (size_t)(n0 + ra) * lda + kbase + co, (char*)Bs + (r * 4 + w) * 1024);
    }
    __syncthreads();
#pragma unroll
    for (int kk = 0; kk < 2; ++kk) {
      short8 af[4], bfr[4];
#pragma unroll
      for (int i = 0; i < 4; ++i) {
        int ar = wm + i * 16 + l15;
        af[i] = *(const short8*)&As[ar * 64 + (((kk * 4 + l4) ^ (ar & 7)) * 8)];
        int br = wn + i * 16 + l15;
        bfr[i] = *(const short8*)&Bs[br * 64 + (((kk * 4 + l4) ^ (br & 7)) * 8)];
      }
#pragma unroll
      for (int i = 0; i < 4; ++i)
#pragma unroll
        for (int j = 0; j < 4; ++j)
          acc[i][j] = __builtin_amdgcn_mfma_f32_16x16x32_bf16(af[i], bfr[j], acc[i][j], 0, 0, 0);
    }
    __syncthreads();
  }
  const bool z0 = (blockIdx.z == 0);
  const size_t MN = (size_t)M * N;
#pragma unroll
  for (int i = 0; i < 4; ++i) {
#pragma unroll
    for (int j = 0; j < 4; ++j) {
      const int gn = n0 + wn + j * 16 + l15;
      float bv = bias[gn];
      if constexpr (EPI == 2) {
        if (!z0) bv = 0.f;                       // bias added once, by chunk 0
      }
#pragma unroll
      for (int r = 0; r < 4; ++r) {
        const int gm = m0 + wm + i * 16 + l4 * 4 + r;
        if (gm < M) {
          float v = acc[i][j][r] + bv;
          if constexpr (EPI == 1) v = fmaxf(v, 0.f);
          if constexpr (EPI == 2) {
            if (z0) {
              Cres[(size_t)gm * N + gn] += v;    // sole writer of Cres in this dispatch
            } else {
              part[(size_t)(blockIdx.z - 1) * MN + (size_t)gm * N + gn] = v;
            }
          } else if constexpr (EPI == 3) {
            if (gn < 1024) {
              Cbf[(size_t)gm * N + gn] = f2bf(v);
            } else {
              int b = gm / 513, t = gm - b * 513;         // gm < 8208 so b < 16
              vT[(size_t)(b * 512 + (gn - 1024)) * 528 + t] = f2bf(v);
            }
          } else {
            Cbf[(size_t)gm * N + gn] = f2bf(v);
          }
        }
      }
    }
  }
}

// ---------------- split-K combine: x += P0 + P1 + P2 over 8208*512 f32 ----------------
__global__ __launch_bounds__(256) void reduce3(const float* __restrict__ p,
                                               float* __restrict__ x) {
  const size_t PN = 8208ull * 512;
  size_t i = ((size_t)blockIdx.x * 256 + threadIdx.x) * 4;   // grid sized exactly: 4104*256*4 = PN
  float4 a = *(const float4*)(x + i);
  float4 b0 = *(const float4*)(p + i);
  float4 b1 = *(const float4*)(p + PN + i);
  float4 b2 = *(const float4*)(p + 2 * PN + i);
  a.x += b0.x + b1.x + b2.x;
  a.y += b0.y + b1.y + b2.y;
  a.z += b0.z + b1.z + b2.z;
  a.w += b0.w + b1.w + b2.w;
  *(float4*)(x + i) = a;
}

// ---------------- flash attention (no V transpose in-kernel; fixed-max softmax) -------------
// qkv bf16 [8320][1536] (cols: q h*64+dk | 512+k). vT bf16 [16*512][528] rows b*512+h*64+dv.
// o bf16 [8320][512] col h*64+dv. grid (9 qtiles, 128 bh), 4 waves, 16 q rows per wave.
__global__ __launch_bounds__(256) void attn_kernel(const unsigned short* __restrict__ qkv,
                                                   const unsigned short* __restrict__ vT,
                                                   unsigned short* __restrict__ o) {
  const int qt = blockIdx.x, bh = blockIdx.y;
  const int b = bh >> 3, hh = bh & 7;
  const int tid = threadIdx.x, w = tid >> 6, lane = tid & 63;
  const int l15 = lane & 15, l4 = lane >> 4;
  __shared__ __align__(16) unsigned short Ks[64 * 64];   // K rows, XOR-swizzled 16B chunks
  __shared__ __align__(16) unsigned short Vs[64 * 64];   // V^T rows, XOR-swizzled
  __shared__ __align__(16) unsigned short Ps[64 * 72];   // P [q][kv] (wave-private rows)
  const int q0 = qt * 64;
  const size_t qbase = (size_t)b * 513 * 1536;
  short8 qf[2];
  {
    const unsigned short* qp =
        qkv + qbase + (size_t)(q0 + w * 16 + l15) * 1536 + hh * 64 + l4 * 8;
    qf[0] = *(const short8*)qp;
    qf[1] = *(const short8*)(qp + 32);
  }
  f32x4 oacc[4] = {};
  float lpart[4] = {};
  for (int kvt = 0; kvt < 9; ++kvt) {
    const int kv0 = kvt * 64;
#pragma unroll
    for (int r = 0; r < 2; ++r) {     // stage K-tile + V^T-tile via global_load_lds
      int ol = (r * 4 + w) * 1024 + lane * 16;
      int rk = ol >> 7, cp = (ol >> 4) & 7;
      int sw = (cp ^ (rk & 7)) * 8;
      lds16(qkv + qbase + (size_t)(kv0 + rk) * 1536 + 512 + hh * 64 + sw,
            (char*)Ks + ol);
      lds16(vT + (size_t)(bh * 64 + rk) * 528 + kv0 + sw, (char*)Vs + ol);
    }
    __syncthreads();
    f32x4 sacc[4] = {};
#pragma unroll
    for (int kk = 0; kk < 2; ++kk)
#pragma unroll
      for (int nf = 0; nf < 4; ++nf) {
        int kr = nf * 16 + l15;
        short8 kf = *(const short8*)&Ks[kr * 64 + (((kk * 4 + l4) ^ (kr & 7)) * 8)];
        sacc[nf] = __builtin_amdgcn_mfma_f32_16x16x32_bf16(qf[kk], kf, sacc[nf], 0, 0, 0);
      }
    // fixed-max softmax: p = exp(s/8) (scores bounded by model scale), masked cols -> 0
#pragma unroll
    for (int nf = 0; nf < 4; ++nf) {
      const bool valid = (kv0 + nf * 16 + l15) < 513;
#pragma unroll
      for (int r = 0; r < 4; ++r) {
        float p = valid ? __expf(sacc[nf][r] * 0.125f) : 0.f;
        lpart[r] += p;
        Ps[(w * 16 + l4 * 4 + r) * 72 + nf * 16 + l15] = f2bf(p);
      }
    }
    // P rows are wave-private: no barrier needed (compiler orders via lgkmcnt)
#pragma unroll
    for (int kk = 0; kk < 2; ++kk) {
      short8 pa = *(const short8*)&Ps[(w * 16 + l15) * 72 + kk * 32 + l4 * 8];
#pragma unroll
      for (int nf = 0; nf < 4; ++nf) {
        int dvr = nf * 16 + l15;
        short8 vf = *(const short8*)&Vs[dvr * 64 + (((kk * 4 + l4) ^ (dvr & 7)) * 8)];
        oacc[nf] = __builtin_amdgcn_mfma_f32_16x16x32_bf16(pa, vf, oacc[nf], 0, 0, 0);
      }
    }
    __syncthreads();
  }
  // one final row-sum reduce across the 16 lanes sharing l4
#pragma unroll
  for (int d = 1; d < 16; d <<= 1)
#pragma unroll
    for (int r = 0; r < 4; ++r) lpart[r] += __shfl_xor(lpart[r], d);
#pragma unroll
  for (int nf = 0; nf < 4; ++nf)
#pragma unroll
    for (int r = 0; r < 4; ++r) {
      int q = q0 + w * 16 + l4 * 4 + r;
      if (q < 513) {
        float val = oacc[nf][r] / lpart[r];
        o[((size_t)b * 513 + q) * 512 + hh * 64 + nf * 16 + l15] = f2bf(val);
      }
    }
}

// ---------------- classifier head (f32 output) ----------------
__global__ void cls_kernel(const float* __restrict__ x, const float* __restrict__ Wc1,
                           const float* __restrict__ bc1, const float* __restrict__ Wc2,
                           const float* __restrict__ bc2, float* __restrict__ out) {
  int b = blockIdx.x, j = threadIdx.x;   // 64 threads
  const float* xr = x + (size_t)b * 513 * 512;
  float acc = bc1[j];
  for (int d = 0; d < 512; ++d) acc += xr[d] * Wc1[d * 64 + j];
  acc = fmaxf(acc, 0.f);
  __shared__ float hid[64];
  hid[j] = acc;
  __syncthreads();
  if (j < 5) {
    float lg = bc2[j];
#pragma unroll
    for (int d2 = 0; d2 < 64; ++d2) lg += hid[d2] * Wc2[d2 * 5 + j];
    out[b * 5 + j] = lg;
  }
}

// ---------------- host ----------------
extern "C" void kernel_launch(void* const* d_in, const int* in_sizes, int n_in,
                              void* d_out, int out_size, void* d_ws, size_t ws_size,
                              hipStream_t stream) {
  const int* ids = (const int*)d_in[0];
  const float* emb = (const float*)d_in[2];
  const float* cls = (const float*)d_in[3];
  const float* ln1g = (const float*)d_in[4];
  const float* ln1b = (const float*)d_in[5];
  const float* ln2g = (const float*)d_in[6];
  const float* ln2b = (const float*)d_in[7];
  const float* Wq = (const float*)d_in[8];
  const float* bq = (const float*)d_in[9];
  const float* Wk = (const float*)d_in[10];
  const float* bk = (const float*)d_in[11];
  const float* Wv = (const float*)d_in[12];
  const float* bv = (const float*)d_in[13];
  const float* Wo = (const float*)d_in[14];
  const float* bo = (const float*)d_in[15];
  const float* W1 = (const float*)d_in[16];
  const float* b1 = (const float*)d_in[17];
  const float* W2 = (const float*)d_in[18];
  const float* b2 = (const float*)d_in[19];
  const float* Wc1 = (const float*)d_in[20];
  const float* bc1 = (const float*)d_in[21];
  const float* Wc2 = (const float*)d_in[22];
  const float* bc2 = (const float*)d_in[23];

  char* ws = (char*)d_ws;
  size_t off = 0;
  auto alloc = [&](size_t bytes) {
    char* p = ws + off;
    off += (bytes + 255) & ~(size_t)255;
    return p;
  };
  const size_t QKV_ELEMS = 8320ull * 1536;           // big's qkv view
  const size_t VT_ELEMS = 16ull * 512 * 528 + 528;   // vT + 1 spill row
  const size_t FFN_ELEMS = 8320ull * 2048;           // ffn hidden view (aliases qkv+vT)
  const size_t BIGU = (QKV_ELEMS + VT_ELEMS > FFN_ELEMS) ? QKV_ELEMS + VT_ELEMS : FFN_ELEMS;

  unsigned short* wqkvT = (unsigned short*)alloc(6ull * 1536 * 512 * 2);
  unsigned short* woT = (unsigned short*)alloc(6ull * 512 * 512 * 2);
  unsigned short* w1T = (unsigned short*)alloc(6ull * 2048 * 512 * 2);
  unsigned short* w2T = (unsigned short*)alloc(6ull * 512 * 2048 * 2);
  float* bqkv = (float*)alloc(6ull * 1536 * 4);
  float* x = (float*)alloc(8208ull * 512 * 4);
  unsigned short* hbuf = (unsigned short*)alloc(8320ull * 512 * 2);
  unsigned short* obuf = (unsigned short*)alloc(8320ull * 512 * 2);
  unsigned short* big = (unsigned short*)alloc(BIGU * 2);
  float* fpart = (float*)alloc(3ull * 8208 * 512 * 4);   // split-K partials (chunks 1..3)
  unsigned short* vT = big + QKV_ELEMS;
  if (off > ws_size) return;

  // zero pads (NaN hygiene): GEMM A-row pads, big K/Q pad rows, full vT
  hipMemsetAsync(hbuf + 8208ull * 512, 0, 112ull * 512 * 2, stream);
  hipMemsetAsync(obuf + 8208ull * 512, 0, 112ull * 512 * 2, stream);
  hipMemsetAsync(big + 8208ull * 1536, 0, 112ull * 1536 * 2, stream);
  hipMemsetAsync(vT, 0, VT_ELEMS * 2, stream);

  pack_qkvT<<<dim3(48, 16, 6), dim3(32, 8), 0, stream>>>(Wq, Wk, Wv, wqkvT);
  transpose_g<<<dim3(16, 16, 6), dim3(32, 8), 0, stream>>>(Wo, woT, 512, 512);
  transpose_g<<<dim3(64, 16, 6), dim3(32, 8), 0, stream>>>(W1, w1T, 512, 2048);
  transpose_g<<<dim3(16, 64, 6), dim3(32, 8), 0, stream>>>(W2, w2T, 2048, 512);
  pack_bias<<<36, 256, 0, stream>>>(bq, bk, bv, bqkv);
  embed_kernel<<<16416, 256, 0, stream>>>(ids, emb, cls, x);

  for (int l = 0; l < 6; ++l) {
    ln_kernel<<<2052, 256, 0, stream>>>(x, ln1g + l * 512, ln1b + l * 512, hbuf);
    gemm_bt<3><<<dim3(65, 12), 256, 0, stream>>>(hbuf, wqkvT + (size_t)l * 1536 * 512,
                                                 bqkv + l * 1536, big, nullptr, vT,
                                                 nullptr, 8208, 1536, 512, 512);
    attn_kernel<<<dim3(9, 128), 256, 0, stream>>>(big, vT, obuf);
    gemm_bt<2><<<dim3(65, 4), 256, 0, stream>>>(obuf, woT + (size_t)l * 512 * 512,
                                                bo + l * 512, nullptr, x, nullptr,
                                                nullptr, 8208, 512, 512, 512);
    ln_kernel<<<2052, 256, 0, stream>>>(x, ln2g + l * 512, ln2b + l * 512, hbuf);
    gemm_bt<1><<<dim3(65, 16), 256, 0, stream>>>(hbuf, w1T + (size_t)l * 2048 * 512,
                                                 b1 + l * 2048, big, nullptr, nullptr,
                                                 nullptr, 8208, 2048, 512, 512);
    // FFN2 split-K x4: K=2048 -> 4 chunks of 512; chunk 0 += into x, chunks 1-3 -> fpart
    gemm_bt<2><<<dim3(65, 4, 4), 256, 0, stream>>>(big, w2T + (size_t)l * 512 * 2048,
                                                   b2 + l * 512, nullptr, x, nullptr,
                                                   fpart, 8208, 512, 512, 2048);
    reduce3<<<4104, 256, 0, stream>>>(fpart, x);
  }
  cls_kernel<<<16, 64, 0, stream>>>(x, Wc1, bc1, Wc2, bc2, (float*)d_out);
}

// Round 2
// 1291.909 us; speedup vs baseline: 1.0744x; 1.0662x over previous
//
#include <hip/hip_runtime.h>
#include <math.h>

#define DEV __device__ __forceinline__

typedef __attribute__((ext_vector_type(8))) short short8;   // 8 bf16 = 4 VGPRs (MFMA frag)
typedef __attribute__((ext_vector_type(4))) float f32x4;    // MFMA 16x16 accum

DEV unsigned short f2bf(float f) {
  union { float f; unsigned int i; } v; v.f = f;
  unsigned int r = v.i + 0x7fffu + ((v.i >> 16) & 1u);
  return (unsigned short)(r >> 16);
}

DEV void lds16(const void* g, void* l) {
  __builtin_amdgcn_global_load_lds((__attribute__((address_space(1))) void*)(g),
                                   (__attribute__((address_space(3))) void*)(l), 16, 0, 0);
}

// ---------------- weight prep ----------------

__global__ void transpose_g(const float* __restrict__ src, unsigned short* __restrict__ dst,
                            int Ksz, int Nsz) {
  __shared__ float tile[32][33];
  const int tx = threadIdx.x, ty = threadIdx.y;
  const int n0 = blockIdx.x * 32, k0 = blockIdx.y * 32;
  const size_t base = (size_t)blockIdx.z * Ksz * Nsz;
#pragma unroll
  for (int i = 0; i < 4; ++i)
    tile[ty + i * 8][tx] = src[base + (size_t)(k0 + ty + i * 8) * Nsz + n0 + tx];
  __syncthreads();
#pragma unroll
  for (int i = 0; i < 4; ++i)
    dst[base + (size_t)(n0 + ty + i * 8) * Ksz + k0 + tx] = f2bf(tile[tx][ty + i * 8]);
}

// Wq/Wk/Wv (L,H,512,64) -> wqkvT [L][1536][512], col order n = mat*512 + h*64 + dk
__global__ void pack_qkvT(const float* __restrict__ Wq, const float* __restrict__ Wk,
                          const float* __restrict__ Wv, unsigned short* __restrict__ dst) {
  __shared__ float tile[32][33];
  const int tx = threadIdx.x, ty = threadIdx.y;
  const int n0 = blockIdx.x * 32, k0 = blockIdx.y * 32, l = blockIdx.z;
  const int mat = n0 >> 9, hh = (n0 >> 6) & 7, dk0 = n0 & 63;
  const float* W = (mat == 0) ? Wq : (mat == 1) ? Wk : Wv;
  const float* Wl = W + ((size_t)l * 8 + hh) * 512 * 64;
#pragma unroll
  for (int i = 0; i < 4; ++i)
    tile[ty + i * 8][tx] = Wl[(size_t)(k0 + ty + i * 8) * 64 + dk0 + tx];
  __syncthreads();
#pragma unroll
  for (int i = 0; i < 4; ++i)
    dst[(size_t)l * 1536 * 512 + (size_t)(n0 + ty + i * 8) * 512 + k0 + tx] =
        f2bf(tile[tx][ty + i * 8]);
}

__global__ void pack_bias(const float* __restrict__ bq, const float* __restrict__ bk,
                          const float* __restrict__ bv, float* __restrict__ dst) {
  int i = blockIdx.x * 256 + threadIdx.x;
  if (i >= 6 * 1536) return;
  int l = i / 1536, c = i % 1536;
  float v = (c < 512) ? bq[l * 512 + c] : (c < 1024) ? bk[l * 512 + (c - 512)]
                                                     : bv[l * 512 + (c - 1024)];
  dst[i] = v;
}

// ---------------- embed + positional encoding ----------------
__global__ void embed_kernel(const int* __restrict__ ids, const float* __restrict__ emb,
                             const float* __restrict__ cls, float* __restrict__ x) {
  int idx = blockIdx.x * 256 + threadIdx.x;   // over 8208*512
  int m = idx >> 9, d = idx & 511;
  int b = m / 513, t = m % 513;
  float v = (t == 0) ? cls[d] : emb[(size_t)ids[b * 512 + (t - 1)] * 512 + d];
  float fr = -(float)(d & ~1) * (9.2103403719761836f / 512.0f);
  float ang = (float)t * expf(fr);
  float pe = (d & 1) ? cosf(ang) : sinf(ang);
  x[idx] = v + pe;
}

// ---------------- layernorm (+ optional fused split-K reduce): one wave per row ------------
// FUSE=1: x_row += P0_row + P1_row + P2_row (split-K partials from previous FFN2), write x
// back, then LN. Bit-identical summation order to the standalone reduce3.
template <int FUSE>
__global__ __launch_bounds__(256) void ln_kernel(float* __restrict__ x,
                                                 const float* __restrict__ g,
                                                 const float* __restrict__ bb,
                                                 unsigned short* __restrict__ h,
                                                 const float* __restrict__ part) {
  int wid = threadIdx.x >> 6, lane = threadIdx.x & 63;
  int m = blockIdx.x * 4 + wid;
  float* xr = x + (size_t)m * 512;
  float4 a = *(const float4*)(xr + lane * 8);
  float4 c = *(const float4*)(xr + lane * 8 + 4);
  if constexpr (FUSE) {
    const size_t PN = 8208ull * 512;
    const float* p = part + (size_t)m * 512 + lane * 8;
    float4 q0 = *(const float4*)(p),          q0b = *(const float4*)(p + 4);
    float4 q1 = *(const float4*)(p + PN),     q1b = *(const float4*)(p + PN + 4);
    float4 q2 = *(const float4*)(p + 2 * PN), q2b = *(const float4*)(p + 2 * PN + 4);
    a.x += q0.x + q1.x + q2.x;  a.y += q0.y + q1.y + q2.y;
    a.z += q0.z + q1.z + q2.z;  a.w += q0.w + q1.w + q2.w;
    c.x += q0b.x + q1b.x + q2b.x;  c.y += q0b.y + q1b.y + q2b.y;
    c.z += q0b.z + q1b.z + q2b.z;  c.w += q0b.w + q1b.w + q2b.w;
    *(float4*)(xr + lane * 8) = a;
    *(float4*)(xr + lane * 8 + 4) = c;
  }
  float s = a.x + a.y + a.z + a.w + c.x + c.y + c.z + c.w;
  float q = a.x * a.x + a.y * a.y + a.z * a.z + a.w * a.w +
            c.x * c.x + c.y * c.y + c.z * c.z + c.w * c.w;
#pragma unroll
  for (int d = 1; d < 64; d <<= 1) { s += __shfl_xor(s, d); q += __shfl_xor(q, d); }
  float mu = s * (1.f / 512.f);
  float var = q * (1.f / 512.f) - mu * mu;
  float rs = 1.f / sqrtf(var + 1e-5f);
  float4 g0 = *(const float4*)(g + lane * 8), g1 = *(const float4*)(g + lane * 8 + 4);
  float4 b0 = *(const float4*)(bb + lane * 8), b1 = *(const float4*)(bb + lane * 8 + 4);
  short8 ov;
  ov[0] = (short)f2bf((a.x - mu) * rs * g0.x + b0.x);
  ov[1] = (short)f2bf((a.y - mu) * rs * g0.y + b0.y);
  ov[2] = (short)f2bf((a.z - mu) * rs * g0.z + b0.z);
  ov[3] = (short)f2bf((a.w - mu) * rs * g0.w + b0.w);
  ov[4] = (short)f2bf((c.x - mu) * rs * g1.x + b1.x);
  ov[5] = (short)f2bf((c.y - mu) * rs * g1.y + b1.y);
  ov[6] = (short)f2bf((c.z - mu) * rs * g1.z + b1.z);
  ov[7] = (short)f2bf((c.w - mu) * rs * g1.w + b1.w);
  *(short8*)(h + (size_t)m * 512 + lane * 8) = ov;
}

// ---------------- GEMM epilogue (shared by both tile shapes) ----------------
// EPI: 0 = bf16 out, 1 = bf16 relu out, 2 = f32 residual add (+split-K), 3 = qkv
template <int EPI>
DEV void gemm_epilogue(f32x4 (&acc)[4][4], const float* __restrict__ bias,
                       unsigned short* __restrict__ Cbf, float* __restrict__ Cres,
                       unsigned short* __restrict__ vT, float* __restrict__ part,
                       int M, int N, int m0, int n0, int wm, int wn, int l15, int l4,
                       int bz) {
  const bool z0 = (bz == 0);
  const size_t MN = (size_t)M * N;
#pragma unroll
  for (int i = 0; i < 4; ++i) {
#pragma unroll
    for (int j = 0; j < 4; ++j) {
      const int gn = n0 + wn + j * 16 + l15;
      float bv = bias[gn];
      if constexpr (EPI == 2) {
        if (!z0) bv = 0.f;                       // bias added once, by chunk 0
      }
#pragma unroll
      for (int r = 0; r < 4; ++r) {
        const int gm = m0 + wm + i * 16 + l4 * 4 + r;
        if (gm < M) {
          float v = acc[i][j][r] + bv;
          if constexpr (EPI == 1) v = fmaxf(v, 0.f);
          if constexpr (EPI == 2) {
            if (z0) {
              Cres[(size_t)gm * N + gn] += v;    // sole writer of Cres in this dispatch
            } else {
              part[(size_t)(bz - 1) * MN + (size_t)gm * N + gn] = v;
            }
          } else if constexpr (EPI == 3) {
            if (gn < 1024) {
              Cbf[(size_t)gm * N + gn] = f2bf(v);
            } else {
              int b = gm / 513, t = gm - b * 513;         // gm < 8208 so b < 16
              vT[(size_t)(b * 512 + (gn - 1024)) * 528 + t] = f2bf(v);
            }
          } else {
            Cbf[(size_t)gm * N + gn] = f2bf(v);
          }
        }
      }
    }
  }
}

// ---------------- GEMM 128x128, 256 thr (kept for proj: small-N, needs block count) --------
template <int EPI>
__global__ __launch_bounds__(256) void gemm_bt(const unsigned short* __restrict__ A,
                                               const unsigned short* __restrict__ Bt,
                                               const float* __restrict__ bias,
                                               unsigned short* __restrict__ Cbf,
                                               float* __restrict__ Cres,
                                               unsigned short* __restrict__ vT,
                                               float* __restrict__ part,
                                               int M, int N, int K, int lda) {
  __shared__ __align__(16) unsigned short As[128 * 64];
  __shared__ __align__(16) unsigned short Bs[128 * 64];
  const int tid = threadIdx.x, w = tid >> 6, lane = tid & 63;
  const int l15 = lane & 15, l4 = lane >> 4;
  const int gx = gridDim.x;
  const int nwg = gx * gridDim.y;
  const int id = blockIdx.y * gx + blockIdx.x;
  const int xcd = id & 7, orig = id >> 3;
  const int qq = nwg >> 3, rr = nwg & 7;
  const int newid = (xcd < rr ? xcd * (qq + 1) : rr * (qq + 1) + (xcd - rr) * qq) + orig;
  const int m0 = (newid % gx) * 128, n0 = (newid / gx) * 128;
  const int wm = (w >> 1) * 64, wn = (w & 1) * 64;
  const int kbase = blockIdx.z * K;
  f32x4 acc[4][4] = {};
  const int nk = K >> 6;
  for (int kt = 0; kt < nk; ++kt) {
#pragma unroll
    for (int r = 0; r < 4; ++r) {
      int ol = (r * 4 + w) * 1024 + lane * 16;      // byte offset in 16KB tile
      int ra = ol >> 7, cp = (ol >> 4) & 7;
      int co = ((cp ^ (ra & 7)) * 8) + kt * 64;     // swizzled source chunk (ushort units)
      lds16(A + (size_t)(m0 + ra) * lda + kbase + co, (char*)As + (r * 4 + w) * 1024);
      lds16(Bt + (size_t)(n0 + ra) * lda + kbase + co, (char*)Bs + (r * 4 + w) * 1024);
    }
    __syncthreads();
#pragma unroll
    for (int kk = 0; kk < 2; ++kk) {
      short8 af[4], bfr[4];
#pragma unroll
      for (int i = 0; i < 4; ++i) {
        int ar = wm + i * 16 + l15;
        af[i] = *(const short8*)&As[ar * 64 + (((kk * 4 + l4) ^ (ar & 7)) * 8)];
        int br = wn + i * 16 + l15;
        bfr[i] = *(const short8*)&Bs[br * 64 + (((kk * 4 + l4) ^ (br & 7)) * 8)];
      }
#pragma unroll
      for (int i = 0; i < 4; ++i)
#pragma unroll
        for (int j = 0; j < 4; ++j)
          acc[i][j] = __builtin_amdgcn_mfma_f32_16x16x32_bf16(af[i], bfr[j], acc[i][j], 0, 0, 0);
    }
    __syncthreads();
  }
  gemm_epilogue<EPI>(acc, bias, Cbf, Cres, vT, part, M, N, m0, n0, wm, wn, l15, l4,
                     blockIdx.z);
}

// ---------------- GEMM 128x256, 512 thr (8 waves 2Mx4N) — halves A-side L3 re-reads --------
// Same m97 2-barrier schedule, same XOR swizzle, same per-wave 4x4 frag code.
template <int EPI>
__global__ __launch_bounds__(512) void gemm_wide(const unsigned short* __restrict__ A,
                                                 const unsigned short* __restrict__ Bt,
                                                 const float* __restrict__ bias,
                                                 unsigned short* __restrict__ Cbf,
                                                 float* __restrict__ Cres,
                                                 unsigned short* __restrict__ vT,
                                                 float* __restrict__ part,
                                                 int M, int N, int K, int lda) {
  __shared__ __align__(16) unsigned short As[128 * 64];   // 16 KB
  __shared__ __align__(16) unsigned short Bs[256 * 64];   // 32 KB
  const int tid = threadIdx.x, w = tid >> 6, lane = tid & 63;
  const int l15 = lane & 15, l4 = lane >> 4;
  const int gx = gridDim.x;
  const int nwg = gx * gridDim.y;
  const int id = blockIdx.y * gx + blockIdx.x;
  const int xcd = id & 7, orig = id >> 3;
  const int qq = nwg >> 3, rr = nwg & 7;
  const int newid = (xcd < rr ? xcd * (qq + 1) : rr * (qq + 1) + (xcd - rr) * qq) + orig;
  const int m0 = (newid % gx) * 128, n0 = (newid / gx) * 256;
  const int wm = (w >> 2) * 64, wn = (w & 3) * 64;
  const int kbase = blockIdx.z * K;
  f32x4 acc[4][4] = {};
  const int nk = K >> 6;
  for (int kt = 0; kt < nk; ++kt) {
#pragma unroll
    for (int r = 0; r < 2; ++r) {                   // A: 16 segments x 1KB
      int s = r * 8 + w;
      int ol = s * 1024 + lane * 16;
      int ra = ol >> 7, cp = (ol >> 4) & 7;
      int co = ((cp ^ (ra & 7)) * 8) + kt * 64;
      lds16(A + (size_t)(m0 + ra) * lda + kbase + co, (char*)As + s * 1024);
    }
#pragma unroll
    for (int r = 0; r < 4; ++r) {                   // B: 32 segments x 1KB
      int s = r * 8 + w;
      int ol = s * 1024 + lane * 16;
      int rb = ol >> 7, cp = (ol >> 4) & 7;
      int co = ((cp ^ (rb & 7)) * 8) + kt * 64;
      lds16(Bt + (size_t)(n0 + rb) * lda + kbase + co, (char*)Bs + s * 1024);
    }
    __syncthreads();
#pragma unroll
    for (int kk = 0; kk < 2; ++kk) {
      short8 af[4], bfr[4];
#pragma unroll
      for (int i = 0; i < 4; ++i) {
        int ar = wm + i * 16 + l15;
        af[i] = *(const short8*)&As[ar * 64 + (((kk * 4 + l4) ^ (ar & 7)) * 8)];
        int br = wn + i * 16 + l15;
        bfr[i] = *(const short8*)&Bs[br * 64 + (((kk * 4 + l4) ^ (br & 7)) * 8)];
      }
#pragma unroll
      for (int i = 0; i < 4; ++i)
#pragma unroll
        for (int j = 0; j < 4; ++j)
          acc[i][j] = __builtin_amdgcn_mfma_f32_16x16x32_bf16(af[i], bfr[j], acc[i][j], 0, 0, 0);
    }
    __syncthreads();
  }
  gemm_epilogue<EPI>(acc, bias, Cbf, Cres, vT, part, M, N, m0, n0, wm, wn, l15, l4,
                     blockIdx.z);
}

// ---------------- split-K combine (only needed after the last layer) ----------------
__global__ __launch_bounds__(256) void reduce3(const float* __restrict__ p,
                                               float* __restrict__ x) {
  const size_t PN = 8208ull * 512;
  size_t i = ((size_t)blockIdx.x * 256 + threadIdx.x) * 4;   // 4104*256*4 = PN exactly
  float4 a = *(const float4*)(x + i);
  float4 b0 = *(const float4*)(p + i);
  float4 b1 = *(const float4*)(p + PN + i);
  float4 b2 = *(const float4*)(p + 2 * PN + i);
  a.x += b0.x + b1.x + b2.x;
  a.y += b0.y + b1.y + b2.y;
  a.z += b0.z + b1.z + b2.z;
  a.w += b0.w + b1.w + b2.w;
  *(float4*)(x + i) = a;
}

// ---------------- flash attention (no V transpose in-kernel; fixed-max softmax) -------------
__global__ __launch_bounds__(256) void attn_kernel(const unsigned short* __restrict__ qkv,
                                                   const unsigned short* __restrict__ vT,
                                                   unsigned short* __restrict__ o) {
  const int qt = blockIdx.x, bh = blockIdx.y;
  const int b = bh >> 3, hh = bh & 7;
  const int tid = threadIdx.x, w = tid >> 6, lane = tid & 63;
  const int l15 = lane & 15, l4 = lane >> 4;
  __shared__ __align__(16) unsigned short Ks[64 * 64];
  __shared__ __align__(16) unsigned short Vs[64 * 64];
  __shared__ __align__(16) unsigned short Ps[64 * 72];
  const int q0 = qt * 64;
  const size_t qbase = (size_t)b * 513 * 1536;
  short8 qf[2];
  {
    const unsigned short* qp =
        qkv + qbase + (size_t)(q0 + w * 16 + l15) * 1536 + hh * 64 + l4 * 8;
    qf[0] = *(const short8*)qp;
    qf[1] = *(const short8*)(qp + 32);
  }
  f32x4 oacc[4] = {};
  float lpart[4] = {};
  for (int kvt = 0; kvt < 9; ++kvt) {
    const int kv0 = kvt * 64;
#pragma unroll
    for (int r = 0; r < 2; ++r) {
      int ol = (r * 4 + w) * 1024 + lane * 16;
      int rk = ol >> 7, cp = (ol >> 4) & 7;
      int sw = (cp ^ (rk & 7)) * 8;
      lds16(qkv + qbase + (size_t)(kv0 + rk) * 1536 + 512 + hh * 64 + sw,
            (char*)Ks + ol);
      lds16(vT + (size_t)(bh * 64 + rk) * 528 + kv0 + sw, (char*)Vs + ol);
    }
    __syncthreads();
    f32x4 sacc[4] = {};
#pragma unroll
    for (int kk = 0; kk < 2; ++kk)
#pragma unroll
      for (int nf = 0; nf < 4; ++nf) {
        int kr = nf * 16 + l15;
        short8 kf = *(const short8*)&Ks[kr * 64 + (((kk * 4 + l4) ^ (kr & 7)) * 8)];
        sacc[nf] = __builtin_amdgcn_mfma_f32_16x16x32_bf16(qf[kk], kf, sacc[nf], 0, 0, 0);
      }
#pragma unroll
    for (int nf = 0; nf < 4; ++nf) {
      const bool valid = (kv0 + nf * 16 + l15) < 513;
#pragma unroll
      for (int r = 0; r < 4; ++r) {
        float p = valid ? __expf(sacc[nf][r] * 0.125f) : 0.f;
        lpart[r] += p;
        Ps[(w * 16 + l4 * 4 + r) * 72 + nf * 16 + l15] = f2bf(p);
      }
    }
#pragma unroll
    for (int kk = 0; kk < 2; ++kk) {
      short8 pa = *(const short8*)&Ps[(w * 16 + l15) * 72 + kk * 32 + l4 * 8];
#pragma unroll
      for (int nf = 0; nf < 4; ++nf) {
        int dvr = nf * 16 + l15;
        short8 vf = *(const short8*)&Vs[dvr * 64 + (((kk * 4 + l4) ^ (dvr & 7)) * 8)];
        oacc[nf] = __builtin_amdgcn_mfma_f32_16x16x32_bf16(pa, vf, oacc[nf], 0, 0, 0);
      }
    }
    __syncthreads();
  }
#pragma unroll
  for (int d = 1; d < 16; d <<= 1)
#pragma unroll
    for (int r = 0; r < 4; ++r) lpart[r] += __shfl_xor(lpart[r], d);
#pragma unroll
  for (int nf = 0; nf < 4; ++nf)
#pragma unroll
    for (int r = 0; r < 4; ++r) {
      int q = q0 + w * 16 + l4 * 4 + r;
      if (q < 513) {
        float val = oacc[nf][r] / lpart[r];
        o[((size_t)b * 513 + q) * 512 + hh * 64 + nf * 16 + l15] = f2bf(val);
      }
    }
}

// ---------------- classifier head (f32 output) ----------------
__global__ void cls_kernel(const float* __restrict__ x, const float* __restrict__ Wc1,
                           const float* __restrict__ bc1, const float* __restrict__ Wc2,
                           const float* __restrict__ bc2, float* __restrict__ out) {
  int b = blockIdx.x, j = threadIdx.x;   // 64 threads
  const float* xr = x + (size_t)b * 513 * 512;
  float acc = bc1[j];
  for (int d = 0; d < 512; ++d) acc += xr[d] * Wc1[d * 64 + j];
  acc = fmaxf(acc, 0.f);
  __shared__ float hid[64];
  hid[j] = acc;
  __syncthreads();
  if (j < 5) {
    float lg = bc2[j];
#pragma unroll
    for (int d2 = 0; d2 < 64; ++d2) lg += hid[d2] * Wc2[d2 * 5 + j];
    out[b * 5 + j] = lg;
  }
}

// ---------------- host ----------------
extern "C" void kernel_launch(void* const* d_in, const int* in_sizes, int n_in,
                              void* d_out, int out_size, void* d_ws, size_t ws_size,
                              hipStream_t stream) {
  const int* ids = (const int*)d_in[0];
  const float* emb = (const float*)d_in[2];
  const float* cls = (const float*)d_in[3];
  const float* ln1g = (const float*)d_in[4];
  const float* ln1b = (const float*)d_in[5];
  const float* ln2g = (const float*)d_in[6];
  const float* ln2b = (const float*)d_in[7];
  const float* Wq = (const float*)d_in[8];
  const float* bq = (const float*)d_in[9];
  const float* Wk = (const float*)d_in[10];
  const float* bk = (const float*)d_in[11];
  const float* Wv = (const float*)d_in[12];
  const float* bv = (const float*)d_in[13];
  const float* Wo = (const float*)d_in[14];
  const float* bo = (const float*)d_in[15];
  const float* W1 = (const float*)d_in[16];
  const float* b1 = (const float*)d_in[17];
  const float* W2 = (const float*)d_in[18];
  const float* b2 = (const float*)d_in[19];
  const float* Wc1 = (const float*)d_in[20];
  const float* bc1 = (const float*)d_in[21];
  const float* Wc2 = (const float*)d_in[22];
  const float* bc2 = (const float*)d_in[23];

  char* ws = (char*)d_ws;
  size_t off = 0;
  auto alloc = [&](size_t bytes) {
    char* p = ws + off;
    off += (bytes + 255) & ~(size_t)255;
    return p;
  };
  const size_t QKV_ELEMS = 8320ull * 1536;           // big's qkv view
  const size_t VT_ELEMS = 16ull * 512 * 528 + 528;   // vT + 1 spill row
  const size_t FFN_ELEMS = 8320ull * 2048;           // ffn hidden view (aliases qkv+vT)
  const size_t BIGU = (QKV_ELEMS + VT_ELEMS > FFN_ELEMS) ? QKV_ELEMS + VT_ELEMS : FFN_ELEMS;

  unsigned short* wqkvT = (unsigned short*)alloc(6ull * 1536 * 512 * 2);
  unsigned short* woT = (unsigned short*)alloc(6ull * 512 * 512 * 2);
  unsigned short* w1T = (unsigned short*)alloc(6ull * 2048 * 512 * 2);
  unsigned short* w2T = (unsigned short*)alloc(6ull * 512 * 2048 * 2);
  float* bqkv = (float*)alloc(6ull * 1536 * 4);
  float* x = (float*)alloc(8208ull * 512 * 4);
  unsigned short* hbuf = (unsigned short*)alloc(8320ull * 512 * 2);
  unsigned short* obuf = (unsigned short*)alloc(8320ull * 512 * 2);
  unsigned short* big = (unsigned short*)alloc(BIGU * 2);
  float* fpart = (float*)alloc(3ull * 8208 * 512 * 4);   // split-K partials (chunks 1..3)
  unsigned short* vT = big + QKV_ELEMS;
  if (off > ws_size) return;

  // zero pads (NaN hygiene): GEMM A-row pads, big K/Q pad rows, full vT
  hipMemsetAsync(hbuf + 8208ull * 512, 0, 112ull * 512 * 2, stream);
  hipMemsetAsync(obuf + 8208ull * 512, 0, 112ull * 512 * 2, stream);
  hipMemsetAsync(big + 8208ull * 1536, 0, 112ull * 1536 * 2, stream);
  hipMemsetAsync(vT, 0, VT_ELEMS * 2, stream);

  pack_qkvT<<<dim3(48, 16, 6), dim3(32, 8), 0, stream>>>(Wq, Wk, Wv, wqkvT);
  transpose_g<<<dim3(16, 16, 6), dim3(32, 8), 0, stream>>>(Wo, woT, 512, 512);
  transpose_g<<<dim3(64, 16, 6), dim3(32, 8), 0, stream>>>(W1, w1T, 512, 2048);
  transpose_g<<<dim3(16, 64, 6), dim3(32, 8), 0, stream>>>(W2, w2T, 2048, 512);
  pack_bias<<<36, 256, 0, stream>>>(bq, bk, bv, bqkv);
  embed_kernel<<<16416, 256, 0, stream>>>(ids, emb, cls, x);

  for (int l = 0; l < 6; ++l) {
    // ln1: for layers >=1, fuse the previous layer's split-K combine into this pass
    if (l == 0)
      ln_kernel<0><<<2052, 256, 0, stream>>>(x, ln1g + l * 512, ln1b + l * 512, hbuf,
                                             nullptr);
    else
      ln_kernel<1><<<2052, 256, 0, stream>>>(x, ln1g + l * 512, ln1b + l * 512, hbuf,
                                             fpart);
    gemm_wide<3><<<dim3(65, 6), 512, 0, stream>>>(hbuf, wqkvT + (size_t)l * 1536 * 512,
                                                  bqkv + l * 1536, big, nullptr, vT,
                                                  nullptr, 8208, 1536, 512, 512);
    attn_kernel<<<dim3(9, 128), 256, 0, stream>>>(big, vT, obuf);
    gemm_bt<2><<<dim3(65, 4), 256, 0, stream>>>(obuf, woT + (size_t)l * 512 * 512,
                                                bo + l * 512, nullptr, x, nullptr,
                                                nullptr, 8208, 512, 512, 512);
    ln_kernel<0><<<2052, 256, 0, stream>>>(x, ln2g + l * 512, ln2b + l * 512, hbuf,
                                           nullptr);
    gemm_wide<1><<<dim3(65, 8), 512, 0, stream>>>(hbuf, w1T + (size_t)l * 2048 * 512,
                                                  b1 + l * 2048, big, nullptr, nullptr,
                                                  nullptr, 8208, 2048, 512, 512);
    // FFN2 split-K x4: chunk 0 += into x, chunks 1-3 -> fpart (combined by next ln1 / final)
    gemm_wide<2><<<dim3(65, 2, 4), 512, 0, stream>>>(big, w2T + (size_t)l * 512 * 2048,
                                                     b2 + l * 512, nullptr, x, nullptr,
                                                     fpart, 8208, 512, 512, 2048);
  }
  reduce3<<<4104, 256, 0, stream>>>(fpart, x);   // combine layer-5 partials
  cls_kernel<<<16, 64, 0, stream>>>(x, Wc1, bc1, Wc2, bc2, (float*)d_out);
}